// Round 1
// 81.778 us; speedup vs baseline: 1.0228x; 1.0228x over previous
//
#include <hip/hip_runtime.h>
#include <hip/hip_bf16.h>

#define F_DIM 512
#define NT 512
#define DEPTH 5
#define NCOL (NT * DEPTH)   // 2560
#define BATCH 2048

typedef __attribute__((ext_vector_type(8))) short bf16x8;
typedef __attribute__((ext_vector_type(4))) float f32x4;

__device__ __forceinline__ void gl2lds16(const void* g, void* l) {
    __builtin_amdgcn_global_load_lds((const __attribute__((address_space(1))) void*)g,
                                     (__attribute__((address_space(3))) void*)l,
                                     16, 0, 0);
}

// ---------------------------------------------------------------------------
// Kernel 1: prep. Softmax blocks FIRST (0..79, they are the long pole),
// cast blocks behind (80..591). 512 threads/block.
// Softmax lane remap: 32 cols per block -> wave reads 2x128B segments/instr
// (was 4x64B). Wt stores widened to 16B. FP reduction order unchanged
// (16 groups x 32 sequential rows) => bit-identical output vs baseline.
// ---------------------------------------------------------------------------
__global__ __launch_bounds__(512) void prep(const float* __restrict__ x,
                                            const float* __restrict__ fa,
                                            __hip_bfloat16* __restrict__ Xb,
                                            __hip_bfloat16* __restrict__ Wt) {
    if (blockIdx.x >= 80) {
        const size_t i = (size_t)(blockIdx.x - 80) * 512 + threadIdx.x;
        const float4 v = ((const float4*)x)[i];
        union { ushort4 u; __hip_bfloat16 h[4]; } pk;
        pk.h[0] = __float2bfloat16(v.x);
        pk.h[1] = __float2bfloat16(v.y);
        pk.h[2] = __float2bfloat16(v.z);
        pk.h[3] = __float2bfloat16(v.w);
        ((ushort4*)Xb)[i] = pk.u;
        return;
    }
    const int l = threadIdx.x & 31;
    const int g = threadIdx.x >> 5;          // 0..15
    const int col = blockIdx.x * 32 + l;
    const int f0 = g * 32;
    __shared__ float red[16][32];

    float e[32];
    float s = 0.f;
#pragma unroll
    for (int i = 0; i < 32; ++i) {
        e[i] = __expf(fa[(size_t)(f0 + i) * NCOL + col]);
        s += e[i];
    }
    red[g][l] = s;
    __syncthreads();

    float S = 0.f;
#pragma unroll
    for (int gg = 0; gg < 16; ++gg) S += red[gg][l];
    const float inv = 1.0f / S;

    __hip_bfloat16* dst = Wt + (size_t)col * F_DIM + f0;
#pragma unroll
    for (int i = 0; i < 32; i += 8) {
        union { uint4 u; __hip_bfloat16 h[8]; } pk;
#pragma unroll
        for (int jj = 0; jj < 8; ++jj)
            pk.h[jj] = __float2bfloat16(e[i + jj] * inv);
        *(uint4*)(dst + i) = pk.u;
    }
}

// ---------------------------------------------------------------------------
// Kernel 2: fused GEMM + tree routing, v5.
// v4 issued each k-step's global_load_lds and immediately hit the
// __syncthreads full vmcnt(0) drain: 8 naked load-latency exposures/block
// (the m97 barrier-drain stall) with only 8 iterations to amortize.
// v5 = T3-minimum 2-phase LDS double-buffer + T4 counted vmcnt:
//   stage(kt+1 -> buf^1); s_waitcnt vmcnt(7)  [tile kt only — it has had a
//   full compute phase to land]; raw s_barrier; ds_read+MFMA buf; s_barrier.
// LDS 2x28KB = 56KB -> still 2 blocks/CU. Epilogue slab reuses buf0.
// ---------------------------------------------------------------------------
__global__ __launch_bounds__(256, 2) void gemm_tree(const __hip_bfloat16* __restrict__ A,
                                                    const __hip_bfloat16* __restrict__ Bt,
                                                    const float* __restrict__ th,
                                                    const float* __restrict__ lt,
                                                    const float* __restrict__ resp,
                                                    float* __restrict__ out) {
    __shared__ __align__(16) char smem[57344];   // 2 x (As 8KB + Bs 20KB); E slab reuses buf0

    const int tid = threadIdx.x;
    const int w = tid >> 6;
    const int l = tid & 63;
    const int m0 = blockIdx.y * 64;       // batch-row base
    const int n0c = blockIdx.x * 160;     // fv-column base
    const int n0t = blockIdx.x * 32;      // tree base
    const int wm = (w & 1) * 32;
    const int wn = (w >> 1) * 80;

    f32x4 acc[2][5] = {};

    const int srow = l >> 3;              // row within 8-row staging group
    const int schunk = (l & 7) ^ srow;    // xor-swizzled source chunk

    auto stage = [&](int kt, int buf) {
        const int k0 = kt * 64;
        char* base = smem + buf * 28672;
#pragma unroll
        for (int q = 0; q < 2; ++q) {     // As: 8 groups of 8 rows
            const int g = q * 4 + w;
            gl2lds16(A + ((size_t)(m0 + g * 8 + srow) * F_DIM + k0 + schunk * 8),
                     base + g * 8 * 64 * 2);
        }
#pragma unroll
        for (int q = 0; q < 5; ++q) {     // Bs: 20 groups of 8 rows
            const int g = q * 4 + w;
            gl2lds16(Bt + ((size_t)(n0c + g * 8 + srow) * F_DIM + k0 + schunk * 8),
                     base + 8192 + g * 8 * 64 * 2);
        }
    };

    stage(0, 0);
#pragma unroll
    for (int kt = 0; kt < 8; ++kt) {
        const int cur = kt & 1;
        __builtin_amdgcn_sched_barrier(0);
        if (kt < 7) {
            stage(kt + 1, cur ^ 1);       // prefetch next tile into other buffer
            asm volatile("s_waitcnt vmcnt(7)" ::: "memory");   // tile kt landed; kt+1 in flight
        } else {
            asm volatile("s_waitcnt vmcnt(0)" ::: "memory");
        }
        __builtin_amdgcn_s_barrier();
        __builtin_amdgcn_sched_barrier(0);

        const __hip_bfloat16* As = (const __hip_bfloat16*)(smem + cur * 28672);
        const __hip_bfloat16* Bs = As + 4096;   // +8192 bytes
#pragma unroll
        for (int ks = 0; ks < 2; ++ks) {
            const int cb = ks * 4 + (l >> 4);
            bf16x8 af[2], bfr[5];
#pragma unroll
            for (int im = 0; im < 2; ++im) {
                const int r = wm + im * 16 + (l & 15);
                af[im] = *(const bf16x8*)(As + r * 64 + ((cb ^ (r & 7)) * 8));
            }
#pragma unroll
            for (int in = 0; in < 5; ++in) {
                const int r = wn + in * 16 + (l & 15);
                bfr[in] = *(const bf16x8*)(Bs + r * 64 + ((cb ^ (r & 7)) * 8));
            }
#pragma unroll
            for (int im = 0; im < 2; ++im)
#pragma unroll
                for (int in = 0; in < 5; ++in)
                    acc[im][in] = __builtin_amdgcn_mfma_f32_16x16x32_bf16(
                        af[im], bfr[in], acc[im][in], 0, 0, 0);
        }
        __builtin_amdgcn_sched_barrier(0);
        __builtin_amdgcn_s_barrier();
    }
    __builtin_amdgcn_sched_barrier(0);

    // ---- tree epilogue (unchanged from v4) ----
    float* E = (float*)smem;              // [32][161], reuses buf0
    const int tree = tid & 31;            // local tree 0..31
    const int rg = tid >> 5;              // row-group 0..7 (4 slab rows each)
    const int gt = n0t + tree;

    float al[DEPTH], be[DEPTH];
#pragma unroll
    for (int j = 0; j < DEPTH; ++j) {
        const float a = 0.5f * __expf(-lt[gt * DEPTH + j]);
        al[j] = a;
        be[j] = 0.5f - th[gt * DEPTH + j] * a;
    }
    float rs[32];
#pragma unroll
    for (int i = 0; i < 32; ++i) rs[i] = resp[gt * 32 + i];

    const int PAD = 161;
#pragma unroll
    for (int im = 0; im < 2; ++im) {
#pragma unroll
        for (int in = 0; in < 5; ++in) {
            const int scol = wn + in * 16 + (l & 15);
#pragma unroll
            for (int r = 0; r < 4; ++r) {
                const int sr = (w & 1) * 16 + (l >> 4) * 4 + r;
                E[sr * PAD + scol] = acc[im][in][r];
            }
        }
        __syncthreads();

#pragma unroll
        for (int rr = 0; rr < 4; ++rr) {
            const int s = rg * 4 + rr;                       // slab row 0..31
            const int gb = m0 + ((s < 16) ? (im * 16 + s) : (32 + im * 16 + (s - 16)));
            const float* f = E + s * PAD + tree * 5;
            float c1[DEPTH];
#pragma unroll
            for (int j = 0; j < DEPTH; ++j) {
                const float v = fmaf(al[j], f[j], be[j]);
                c1[j] = fminf(fmaxf(v, 0.f), 1.f);
            }
            float s16[16], s8[8], s4[4], s2[2];
#pragma unroll
            for (int m = 0; m < 16; ++m) s16[m] = fmaf(c1[0], rs[2*m+1] - rs[2*m], rs[2*m]);
#pragma unroll
            for (int m = 0; m < 8; ++m)  s8[m]  = fmaf(c1[1], s16[2*m+1] - s16[2*m], s16[2*m]);
#pragma unroll
            for (int m = 0; m < 4; ++m)  s4[m]  = fmaf(c1[2], s8[2*m+1] - s8[2*m], s8[2*m]);
#pragma unroll
            for (int m = 0; m < 2; ++m)  s2[m]  = fmaf(c1[3], s4[2*m+1] - s4[2*m], s4[2*m]);
            out[(size_t)gb * NT + gt] = fmaf(c1[4], s2[1] - s2[0], s2[0]);
        }
        __syncthreads();
    }
}

// ---------------------------------------------------------------------------
extern "C" void kernel_launch(void* const* d_in, const int* in_sizes, int n_in,
                              void* d_out, int out_size, void* d_ws, size_t ws_size,
                              hipStream_t stream) {
    const float* x    = (const float*)d_in[0];
    const float* fa   = (const float*)d_in[1];
    const float* th   = (const float*)d_in[2];
    const float* lt   = (const float*)d_in[3];
    const float* resp = (const float*)d_in[4];
    // d_in[5] = path_map: deterministic oblivious layout, hardcoded in epilogue.

    char* ws = (char*)d_ws;
    __hip_bfloat16* Wt = (__hip_bfloat16*)(ws);                 // 2560*512*2 = 2.62 MB
    __hip_bfloat16* Xb = (__hip_bfloat16*)(ws + (4u << 20));    // 2048*512*2 = 2.10 MB
    float* out = (float*)d_out;

    hipLaunchKernelGGL(prep, dim3(80 + 512), dim3(512), 0, stream, x, fa, Xb, Wt);
    hipLaunchKernelGGL(gemm_tree, dim3(NCOL / 160, BATCH / 64), dim3(256), 0, stream,
                       Xb, Wt, th, lt, resp, out);
}